// Round 3
// baseline (547.226 us; speedup 1.0000x reference)
//
#include <hip/hip_runtime.h>
#include <math.h>

typedef unsigned short u16;
typedef unsigned int   u32;

#define SS_    4
#define NH     4
#define Dh     32
#define Cdim   128
#define Ntok   64
#define WTOT   2048
#define Mrows  131072   // WTOT * Ntok
#define HIDDEN 512
#define PSTR   72       // P LDS row stride (u16): 144 B, 16-B aligned, low-conflict
#define HSTR   72       // MLP per-wave H row stride (u16): 144 B, 16-B aligned

typedef __bf16 bf16x8 __attribute__((ext_vector_type(8)));
typedef float  f32x4  __attribute__((ext_vector_type(4)));

__device__ __forceinline__ float bf2f(u16 u){
    union {u32 i; float f;} v; v.i = ((u32)u) << 16; return v.f;
}
__device__ __forceinline__ u16 f2bf(float f){
    union {float f; u32 i;} v; v.f = f;
    u32 x = v.i;
    return (u16)((x + 0x7fffu + ((x >> 16) & 1u)) >> 16);
}

// token (windowed row) -> original token index (bijection, shift +4 both dims)
__device__ __forceinline__ int map_row_to_token(int r){
    int w = r >> 6, n = r & 63;
    int b = w >> 8, win = w & 255;
    int wy = win >> 4, wx = win & 15;
    int iy = n >> 3, ix = n & 7;
    int ro = (wy*8 + iy + SS_) & 127;
    int co = (wx*8 + ix + SS_) & 127;
    return (b << 14) + (ro << 7) + co;
}

// ---------------- fp32 -> bf16 weight conversion ----------------
__global__ void __launch_bounds__(256) cvt_kernel(const float* __restrict__ src,
        u16* __restrict__ dst, int n)
{
    int i = blockIdx.x * 256 + threadIdx.x;
    if (i < n) dst[i] = f2bf(src[i]);
}

// ---------------- bias+mask table: bm[cls][h][row][col], 4*4*64*64 fp32 ----------
__global__ void __launch_bounds__(256) bm_kernel(const float* __restrict__ rpb,
        float* __restrict__ bmt)
{
    int e = blockIdx.x * 256 + threadIdx.x;     // 65536 total
    int cls = e >> 14, h = (e >> 12) & 3, row = (e >> 6) & 63, col = e & 63;
    int iy = row >> 3, ix = row & 7, jy = col >> 3, jx = col & 7;
    int bidx = (iy - jy + 7)*15 + (ix - jx + 7);
    float bias = rpb[bidx*NH + h];
    int ybit = cls >> 1, xbit = cls & 1;
    int ri = (ybit ? (iy < 4 ? 1 : 2) : 0)*3 + (xbit ? (ix < 4 ? 1 : 2) : 0);
    int rj = (ybit ? (jy < 4 ? 1 : 2) : 0)*3 + (xbit ? (jx < 4 ? 1 : 2) : 0);
    bmt[e] = bias + ((ri != rj) ? -100.0f : 0.0f);
}

// ---------------- LayerNorm 1 (fp32 in, bf16 windowed out) ----------------
__global__ void __launch_bounds__(128) ln1_kernel(const float* __restrict__ xin,
        const float* __restrict__ g, const float* __restrict__ bsh,
        u16* __restrict__ outp)
{
    int t = blockIdx.x;
    int c = threadIdx.x;
    int src = map_row_to_token(t);
    float val = xin[(size_t)src*Cdim + c];
    float s = val, s2 = val*val;
    #pragma unroll
    for (int off = 32; off >= 1; off >>= 1){
        s  += __shfl_xor(s,  off, 64);
        s2 += __shfl_xor(s2, off, 64);
    }
    __shared__ float red[4];
    int wv = threadIdx.x >> 6;
    if ((threadIdx.x & 63) == 0){ red[wv*2] = s; red[wv*2+1] = s2; }
    __syncthreads();
    float ts = red[0] + red[2], ts2 = red[1] + red[3];
    float mean = ts * (1.0f/128.0f);
    float var  = ts2 * (1.0f/128.0f) - mean*mean;
    float inv  = rsqrtf(var + 1e-5f);
    outp[(size_t)t*Cdim + c] = f2bf((val - mean) * inv * g[c] + bsh[c]);
}

// ------- fused: window-reverse + unshift + residual -> x2 (fp32), then LN2 -> bf16
// NOTE: projout, x2, ln2out are pairwise-DISJOINT buffers (round-5 race fix).
__global__ void __launch_bounds__(128) resln_kernel(const float* __restrict__ x,
        const u16* __restrict__ projout,
        const float* __restrict__ g, const float* __restrict__ bsh,
        float* __restrict__ x2, u16* __restrict__ outp)
{
    int t = blockIdx.x;      // token index
    int c = threadIdx.x;
    int b = t >> 14, ro = (t >> 7) & 127, co = t & 127;
    int y  = (ro + 128 - SS_) & 127;
    int xq = (co + 128 - SS_) & 127;
    int r = (((b << 8) | ((y >> 3) << 4) | (xq >> 3)) << 6) + (y & 7)*8 + (xq & 7);
    float val = x[(size_t)t*Cdim + c] + bf2f(projout[(size_t)r*Cdim + c]);
    x2[(size_t)t*Cdim + c] = val;
    float s = val, s2 = val*val;
    #pragma unroll
    for (int off = 32; off >= 1; off >>= 1){
        s  += __shfl_xor(s,  off, 64);
        s2 += __shfl_xor(s2, off, 64);
    }
    __shared__ float red[4];
    int wv = threadIdx.x >> 6;
    if ((threadIdx.x & 63) == 0){ red[wv*2] = s; red[wv*2+1] = s2; }
    __syncthreads();
    float ts = red[0] + red[2], ts2 = red[1] + red[3];
    float mean = ts * (1.0f/128.0f);
    float var  = ts2 * (1.0f/128.0f) - mean*mean;
    float inv  = rsqrtf(var + 1e-5f);
    outp[(size_t)t*Cdim + c] = f2bf((val - mean) * inv * g[c] + bsh[c]);
}

// ---------------- Registers-only MFMA GEMM: C = A[M,K] @ Bw[N,K]^T + bias -------
// 128x128 tile, 4 waves 2x2 (each 64x64). No LDS, no barriers.
// MODE 0: qkv scatter (q scaled, k normal, v TRANSPOSED [w][h][d][n])
// MODE 1: plain bf16
template<int K, int N, int MODE>
__global__ void __launch_bounds__(256) gemm_kernel(
        const u16* __restrict__ A, const u16* __restrict__ Bw,
        const float* __restrict__ bias,
        void* __restrict__ o0, u16* __restrict__ o1, u16* __restrict__ o2,
        const float* __restrict__ resid)
{
    int t = threadIdx.x;
    int wave = t >> 6, lane = t & 63;
    int wr = wave & 1, wc = wave >> 1;
    int m = lane & 15, quad = lane >> 4;
    size_t rowbase = (size_t)blockIdx.x * 128 + wr*64;
    size_t nb      = (size_t)blockIdx.y * 128 + wc*64;

    f32x4 acc[4][4] = {};

    #pragma unroll 4
    for (int s = 0; s < K/32; s++){
        bf16x8 aq[4], bk[4];
        #pragma unroll
        for (int i = 0; i < 4; i++)
            aq[i] = *(const bf16x8*)&A[(rowbase + i*16 + m)*K + s*32 + quad*8];
        #pragma unroll
        for (int j = 0; j < 4; j++)
            bk[j] = *(const bf16x8*)&Bw[(nb + j*16 + m)*K + s*32 + quad*8];
        #pragma unroll
        for (int i = 0; i < 4; i++)
            #pragma unroll
            for (int j = 0; j < 4; j++)
                acc[i][j] = __builtin_amdgcn_mfma_f32_16x16x32_bf16(
                                aq[i], bk[j], acc[i][j], 0, 0, 0);
    }

    #pragma unroll
    for (int i = 0; i < 4; i++){
        #pragma unroll
        for (int j = 0; j < 4; j++){
            int c = (int)nb + j*16 + m;
            float bia = bias[c];
            #pragma unroll
            for (int rg = 0; rg < 4; rg++){
                int r = (int)rowbase + i*16 + quad*4 + rg;
                float v = acc[i][j][rg] + bia;
                if (MODE == 0){
                    int which = c >> 7;          // 0=q 1=k 2=v
                    int h = (c >> 5) & 3;
                    int d = c & 31;
                    int w = r >> 6, n = r & 63;
                    if (which == 0){
                        ((u16*)o0)[((size_t)(w*NH + h)*Ntok + n)*Dh + d] =
                            f2bf(v * 0.17677669529663687f);
                    } else if (which == 1){
                        o1[((size_t)(w*NH + h)*Ntok + n)*Dh + d] = f2bf(v);
                    } else {   // v transposed: [w][h][d][n]
                        o2[((size_t)(w*NH + h)*Dh + d)*Ntok + n] = f2bf(v);
                    }
                } else {
                    ((u16*)o0)[(size_t)r*N + c] = f2bf(v);
                }
            }
        }
    }
}

// ---------------- Fused MLP: out = x2 + GELU(ln2out @ W1^T + b1) @ W2^T + b2 ----
// 1024 blocks x 256 threads. Wave w owns output rows [blk*128 + w*32, +32):
// fully wave-private -> ZERO barriers. A slices live in registers (each lane
// only touches cols {s*32+quad*8..+8} of its 2 rows = 32 VGPRs, loaded once).
// Hidden dim processed in 8 chunks of 64; per chunk: H = GELU(A@W1c^T+b1c)
// -> wave-private LDS (32x72 u16) -> O += H@W2c^T. Same-wave LDS RAW ordering
// is guaranteed via lgkmcnt (no __syncthreads needed, cf. attn P buffer).
__global__ void __launch_bounds__(256) mlp_kernel(
        const u16* __restrict__ A,       // ln2out [Mrows][128] bf16
        const u16* __restrict__ W1,      // fc1w   [512][128]   bf16
        const float* __restrict__ b1,
        const u16* __restrict__ W2,      // fc2w   [128][512]   bf16
        const float* __restrict__ b2,
        const float* __restrict__ resid, // x2     [Mrows][128] fp32
        float* __restrict__ outp)        // out    [Mrows][128] fp32
{
    __shared__ __align__(16) u16 Hsm[4][32*HSTR];   // 18432 B total
    int t = threadIdx.x;
    int w = t >> 6, lane = t & 63;
    int m = lane & 15, quad = lane >> 4;
    size_t trow = (size_t)blockIdx.x * 128 + w*32;
    u16* hs = &Hsm[w][0];

    // A slices -> registers (reused across all 8 hidden chunks)
    bf16x8 areg[2][4];
    #pragma unroll
    for (int i = 0; i < 2; i++)
        #pragma unroll
        for (int s = 0; s < 4; s++)
            areg[i][s] = *(const bf16x8*)&A[(trow + i*16 + m)*Cdim + s*32 + quad*8];

    f32x4 O[2][8] = {};                  // 32 rows x 128 out cols per wave

    for (int kk = 0; kk < 8; kk++){
        // ---- H chunk (32 rows x 64 hidden): Hacc = A @ W1c^T ----
        f32x4 Hacc[2][4] = {};
        #pragma unroll
        for (int s = 0; s < 4; s++){
            bf16x8 bw[4];
            #pragma unroll
            for (int jh = 0; jh < 4; jh++)
                bw[jh] = *(const bf16x8*)&W1[(size_t)(kk*64 + jh*16 + m)*Cdim
                                             + s*32 + quad*8];
            #pragma unroll
            for (int i = 0; i < 2; i++)
                #pragma unroll
                for (int jh = 0; jh < 4; jh++)
                    Hacc[i][jh] = __builtin_amdgcn_mfma_f32_16x16x32_bf16(
                                      areg[i][s], bw[jh], Hacc[i][jh], 0, 0, 0);
        }
        // ---- bias + GELU -> wave-private LDS ----
        #pragma unroll
        for (int i = 0; i < 2; i++){
            #pragma unroll
            for (int jh = 0; jh < 4; jh++){
                int hc = jh*16 + m;
                float bia = b1[kk*64 + hc];
                #pragma unroll
                for (int rg = 0; rg < 4; rg++){
                    int r = i*16 + quad*4 + rg;
                    float v = Hacc[i][jh][rg] + bia;
                    float gl = 0.5f * v * (1.0f + erff(v * 0.70710678118654752f));
                    hs[r*HSTR + hc] = f2bf(gl);
                }
            }
        }
        // ---- O += H @ W2c^T  (k = 64 hidden, 2 steps) ----
        #pragma unroll
        for (int s2 = 0; s2 < 2; s2++){
            bf16x8 pa[2];
            #pragma unroll
            for (int i = 0; i < 2; i++)
                pa[i] = *(const bf16x8*)&hs[(i*16 + m)*HSTR + s2*32 + quad*8];
            #pragma unroll
            for (int jg = 0; jg < 2; jg++){
                bf16x8 bw2[4];
                #pragma unroll
                for (int j = 0; j < 4; j++)
                    bw2[j] = *(const bf16x8*)&W2[(size_t)((jg*4 + j)*16 + m)*HIDDEN
                                                 + kk*64 + s2*32 + quad*8];
                #pragma unroll
                for (int i = 0; i < 2; i++)
                    #pragma unroll
                    for (int j = 0; j < 4; j++)
                        O[i][jg*4 + j] = __builtin_amdgcn_mfma_f32_16x16x32_bf16(
                                             pa[i], bw2[j], O[i][jg*4 + j], 0, 0, 0);
            }
        }
    }

    // ---- epilogue: + b2 + residual -> fp32 out ----
    #pragma unroll
    for (int i = 0; i < 2; i++){
        #pragma unroll
        for (int j = 0; j < 8; j++){
            int c = j*16 + m;
            float bia = b2[c];
            #pragma unroll
            for (int rg = 0; rg < 4; rg++){
                size_t r = trow + i*16 + quad*4 + rg;
                outp[r*Cdim + c] = resid[r*Cdim + c] + O[i][j][rg] + bia;
            }
        }
    }
}

// ---------------- MFMA attention: block = window, wave = head ----------------
__global__ void __launch_bounds__(256) attn_kernel(
        const u16* __restrict__ qb, const u16* __restrict__ kb,
        const u16* __restrict__ vt, const float* __restrict__ bmt,
        u16* __restrict__ attno)
{
    __shared__ __align__(16) u16 P[NH][64*PSTR];
    int w = blockIdx.x;
    int win = w & 255;
    int wy = win >> 4, wx = win & 15;
    int cls = ((wy == 15) ? 2 : 0) | ((wx == 15) ? 1 : 0);
    int t = threadIdx.x;
    int h = t >> 6, lane = t & 63;
    int m = lane & 15, quad = lane >> 4;

    const u16* qg = qb + (size_t)(w*NH + h)*2048;   // [n][d]
    const u16* kg = kb + (size_t)(w*NH + h)*2048;   // [n][d]
    const u16* vg = vt + (size_t)(w*NH + h)*2048;   // [d][n] (transposed)
    const float* bm = bmt + (size_t)(cls*NH + h)*4096;

    // S = Q @ K^T  (64x64, one K=32 step)
    bf16x8 aq[4], bk[4];
    #pragma unroll
    for (int i = 0; i < 4; i++)
        aq[i] = *(const bf16x8*)&qg[(i*16 + m)*32 + quad*8];
    #pragma unroll
    for (int j = 0; j < 4; j++)
        bk[j] = *(const bf16x8*)&kg[(j*16 + m)*32 + quad*8];
    f32x4 S[4][4] = {};
    #pragma unroll
    for (int i = 0; i < 4; i++)
        #pragma unroll
        for (int j = 0; j < 4; j++)
            S[i][j] = __builtin_amdgcn_mfma_f32_16x16x32_bf16(
                          aq[i], bk[j], S[i][j], 0, 0, 0);

    // bias+mask add, row softmax (row = i*16 + quad*4 + rg; cols across 16 lanes x 4 j)
    #pragma unroll
    for (int i = 0; i < 4; i++){
        #pragma unroll
        for (int rg = 0; rg < 4; rg++){
            int row = i*16 + quad*4 + rg;
            float s0 = S[i][0][rg] + bm[row*64 +  0 + m];
            float s1 = S[i][1][rg] + bm[row*64 + 16 + m];
            float s2 = S[i][2][rg] + bm[row*64 + 32 + m];
            float s3 = S[i][3][rg] + bm[row*64 + 48 + m];
            float mx = fmaxf(fmaxf(s0, s1), fmaxf(s2, s3));
            mx = fmaxf(mx, __shfl_xor(mx, 1, 64));
            mx = fmaxf(mx, __shfl_xor(mx, 2, 64));
            mx = fmaxf(mx, __shfl_xor(mx, 4, 64));
            mx = fmaxf(mx, __shfl_xor(mx, 8, 64));
            s0 = __expf(s0 - mx); s1 = __expf(s1 - mx);
            s2 = __expf(s2 - mx); s3 = __expf(s3 - mx);
            float sm = s0 + s1 + s2 + s3;
            sm += __shfl_xor(sm, 1, 64);
            sm += __shfl_xor(sm, 2, 64);
            sm += __shfl_xor(sm, 4, 64);
            sm += __shfl_xor(sm, 8, 64);
            float rinv = 1.0f / sm;
            u16* pr = &P[h][row*PSTR];
            pr[ 0 + m] = f2bf(s0 * rinv);
            pr[16 + m] = f2bf(s1 * rinv);
            pr[32 + m] = f2bf(s2 * rinv);
            pr[48 + m] = f2bf(s3 * rinv);
        }
    }
    // per-wave private P rows: same-wave LDS ordering suffices, no barrier

    // O = P @ V  (64x32, two K=32 steps)
    f32x4 O[4][2] = {};
    #pragma unroll
    for (int s2 = 0; s2 < 2; s2++){
        bf16x8 pa[4], bv[2];
        #pragma unroll
        for (int i = 0; i < 4; i++)
            pa[i] = *(const bf16x8*)&P[h][(i*16 + m)*PSTR + s2*32 + quad*8];
        #pragma unroll
        for (int dt = 0; dt < 2; dt++)
            bv[dt] = *(const bf16x8*)&vg[(dt*16 + m)*64 + s2*32 + quad*8];
        #pragma unroll
        for (int i = 0; i < 4; i++)
            #pragma unroll
            for (int dt = 0; dt < 2; dt++)
                O[i][dt] = __builtin_amdgcn_mfma_f32_16x16x32_bf16(
                               pa[i], bv[dt], O[i][dt], 0, 0, 0);
    }

    #pragma unroll
    for (int i = 0; i < 4; i++)
        #pragma unroll
        for (int dt = 0; dt < 2; dt++)
            #pragma unroll
            for (int rg = 0; rg < 4; rg++){
                int token = w*64 + i*16 + quad*4 + rg;
                attno[(size_t)token*Cdim + h*Dh + dt*16 + m] = f2bf(O[i][dt][rg]);
            }
}

extern "C" void kernel_launch(void* const* d_in, const int* in_sizes, int n_in,
                              void* d_out, int out_size, void* d_ws, size_t ws_size,
                              hipStream_t stream) {
    const float* x     = (const float*)d_in[0];
    const float* rpb   = (const float*)d_in[1];
    const float* n1g   = (const float*)d_in[2];
    const float* n1b   = (const float*)d_in[3];
    const float* qkvw  = (const float*)d_in[4];
    const float* qkvb  = (const float*)d_in[5];
    const float* projw = (const float*)d_in[6];
    const float* projb = (const float*)d_in[7];
    const float* n2g   = (const float*)d_in[8];
    const float* n2b   = (const float*)d_in[9];
    const float* fc1w  = (const float*)d_in[10];
    const float* fc1b  = (const float*)d_in[11];
    const float* fc2w  = (const float*)d_in[12];
    const float* fc2b  = (const float*)d_in[13];
    float* out = (float*)d_out;

    if (ws_size < (size_t)230u * 1024u * 1024u) return;

    // Disjoint-lifetime layout (race-free):
    //   region        offset   size   lifetime
    //   ln1out        0        32M    s1 -> s2
    //   projout       0        32M    s4 -> s5   (ln1out dead)
    //   qbuf          32M      32M    s2 -> s3
    //   kbuf          64M      32M    s2 -> s3
    //   vbuf          96M      32M    s2 -> s3
    //   attno         128M     32M    s3 -> s4
    //   x2            128M     64M    s5 -> s6   (attno dead)
    //   ln2out        192M     32M    s5 -> s6
    //   weights/bmt   224M     ~2M    s0 -> end
    char* ws = (char*)d_ws;
    u16*  ln1out  = (u16*)(ws);
    u16*  projout = (u16*)(ws);
    u16*  qbuf    = (u16*)(ws + ((size_t)32  << 20));
    u16*  kbuf    = (u16*)(ws + ((size_t)64  << 20));
    u16*  vbuf    = (u16*)(ws + ((size_t)96  << 20));
    u16*  attno   = (u16*)(ws + ((size_t)128 << 20));
    float* x2     = (float*)(ws + ((size_t)128 << 20));
    u16*  ln2out  = (u16*)(ws + ((size_t)192 << 20));
    u16*  wb      = (u16*)(ws + ((size_t)224 << 20));
    u16*  qkvw_b  = wb;                // 49152
    u16*  projw_b = wb + 49152;        // 16384
    u16*  fc1w_b  = wb + 65536;        // 65536
    u16*  fc2w_b  = wb + 131072;       // 65536
    float* bmt    = (float*)(ws + ((size_t)225 << 20)); // 256 KiB

    // 0. weight conversions + bias/mask table
    cvt_kernel<<<(49152+255)/256, 256, 0, stream>>>(qkvw, qkvw_b, 49152);
    cvt_kernel<<<(16384+255)/256, 256, 0, stream>>>(projw, projw_b, 16384);
    cvt_kernel<<<(65536+255)/256, 256, 0, stream>>>(fc1w, fc1w_b, 65536);
    cvt_kernel<<<(65536+255)/256, 256, 0, stream>>>(fc2w, fc2w_b, 65536);
    bm_kernel<<<256, 256, 0, stream>>>(rpb, bmt);

    // 1. LN1 + shift + window partition
    ln1_kernel<<<Mrows, 128, 0, stream>>>(x, n1g, n1b, ln1out);
    // 2. QKV GEMM (q/k per-head, v transposed)
    gemm_kernel<128, 384, 0><<<dim3(Mrows/128, 3), 256, 0, stream>>>(
        ln1out, qkvw_b, qkvb, qbuf, kbuf, vbuf, nullptr);
    // 3. MFMA windowed attention (block = window)
    attn_kernel<<<WTOT, 256, 0, stream>>>(qbuf, kbuf, vbuf, bmt, attno);
    // 4. proj GEMM
    gemm_kernel<128, 128, 1><<<dim3(Mrows/128, 1), 256, 0, stream>>>(
        attno, projw_b, projb, projout, nullptr, nullptr, nullptr);
    // 5. fused window-reverse + unshift + residual + LN2 (disjoint in/out)
    resln_kernel<<<Mrows, 128, 0, stream>>>(x, projout, n2g, n2b, x2, ln2out);
    // 6. fused MLP: out = x2 + GELU(ln2out @ fc1^T + b1) @ fc2^T + b2
    mlp_kernel<<<Mrows/128, 256, 0, stream>>>(
        ln2out, fc1w_b, fc1b, fc2w_b, fc2b, x2, out);
}

// Round 4
// 488.283 us; speedup vs baseline: 1.1207x; 1.1207x over previous
//
#include <hip/hip_runtime.h>
#include <math.h>

typedef unsigned short u16;
typedef unsigned int   u32;

#define SS_    4
#define NH     4
#define Dh     32
#define Cdim   128
#define Ntok   64
#define WTOT   2048
#define Mrows  131072   // WTOT * Ntok
#define HIDDEN 512
#define PSTR   72       // attn P LDS row stride (u16)
#define OSTR   136      // attn Osm row stride (u16): 272 B, 16-B aligned
#define HPAD   136      // MLP LDS row stride (u16): 272 B, 16-B aligned

typedef __bf16 bf16x8 __attribute__((ext_vector_type(8)));
typedef float  f32x4  __attribute__((ext_vector_type(4)));

__device__ __forceinline__ float bf2f(u16 u){
    union {u32 i; float f;} v; v.i = ((u32)u) << 16; return v.f;
}
__device__ __forceinline__ u16 f2bf(float f){
    union {float f; u32 i;} v; v.f = f;
    u32 x = v.i;
    return (u16)((x + 0x7fffu + ((x >> 16) & 1u)) >> 16);
}

// GELU with A&S 7.1.26 erf approx (max err 1.5e-7): ~14 VALU ops vs erff libcall
__device__ __forceinline__ float fast_gelu(float v){
    float a = v * 0.70710678118654752f;
    float x = fabsf(a);
    float t = 1.0f / (1.0f + 0.3275911f * x);
    float p = ((((1.061405429f*t - 1.453152027f)*t + 1.421413741f)*t
                - 0.284496736f)*t + 0.254829592f)*t;
    float e = __expf(-x*x);
    float er = copysignf(1.0f - p*e, a);
    return 0.5f * v * (1.0f + er);
}

// token (windowed row) -> original token index (bijection, shift +4 both dims)
__device__ __forceinline__ int map_row_to_token(int r){
    int w = r >> 6, n = r & 63;
    int b = w >> 8, win = w & 255;
    int wy = win >> 4, wx = win & 15;
    int iy = n >> 3, ix = n & 7;
    int ro = (wy*8 + iy + SS_) & 127;
    int co = (wx*8 + ix + SS_) & 127;
    return (b << 14) + (ro << 7) + co;
}

// ---------------- fp32 -> bf16 weight conversion ----------------
__global__ void __launch_bounds__(256) cvt_kernel(const float* __restrict__ src,
        u16* __restrict__ dst, int n)
{
    int i = blockIdx.x * 256 + threadIdx.x;
    if (i < n) dst[i] = f2bf(src[i]);
}

// ---------------- bias+mask table: bm[cls][h][row][col], 4*4*64*64 fp32 ----------
__global__ void __launch_bounds__(256) bm_kernel(const float* __restrict__ rpb,
        float* __restrict__ bmt)
{
    int e = blockIdx.x * 256 + threadIdx.x;     // 65536 total
    int cls = e >> 14, h = (e >> 12) & 3, row = (e >> 6) & 63, col = e & 63;
    int iy = row >> 3, ix = row & 7, jy = col >> 3, jx = col & 7;
    int bidx = (iy - jy + 7)*15 + (ix - jx + 7);
    float bias = rpb[bidx*NH + h];
    int ybit = cls >> 1, xbit = cls & 1;
    int ri = (ybit ? (iy < 4 ? 1 : 2) : 0)*3 + (xbit ? (ix < 4 ? 1 : 2) : 0);
    int rj = (ybit ? (jy < 4 ? 1 : 2) : 0)*3 + (xbit ? (jx < 4 ? 1 : 2) : 0);
    bmt[e] = bias + ((ri != rj) ? -100.0f : 0.0f);
}

// ---------------- LayerNorm 1 (fp32 in, bf16 windowed out) ----------------
__global__ void __launch_bounds__(128) ln1_kernel(const float* __restrict__ xin,
        const float* __restrict__ g, const float* __restrict__ bsh,
        u16* __restrict__ outp)
{
    int t = blockIdx.x;
    int c = threadIdx.x;
    int src = map_row_to_token(t);
    float val = xin[(size_t)src*Cdim + c];
    float s = val, s2 = val*val;
    #pragma unroll
    for (int off = 32; off >= 1; off >>= 1){
        s  += __shfl_xor(s,  off, 64);
        s2 += __shfl_xor(s2, off, 64);
    }
    __shared__ float red[4];
    int wv = threadIdx.x >> 6;
    if ((threadIdx.x & 63) == 0){ red[wv*2] = s; red[wv*2+1] = s2; }
    __syncthreads();
    float ts = red[0] + red[2], ts2 = red[1] + red[3];
    float mean = ts * (1.0f/128.0f);
    float var  = ts2 * (1.0f/128.0f) - mean*mean;
    float inv  = rsqrtf(var + 1e-5f);
    outp[(size_t)t*Cdim + c] = f2bf((val - mean) * inv * g[c] + bsh[c]);
}

// ------- fused: window-reverse + unshift + residual -> x2 (fp32), then LN2 -> bf16
__global__ void __launch_bounds__(128) resln_kernel(const float* __restrict__ x,
        const u16* __restrict__ projout,
        const float* __restrict__ g, const float* __restrict__ bsh,
        float* __restrict__ x2, u16* __restrict__ outp)
{
    int t = blockIdx.x;      // token index
    int c = threadIdx.x;
    int b = t >> 14, ro = (t >> 7) & 127, co = t & 127;
    int y  = (ro + 128 - SS_) & 127;
    int xq = (co + 128 - SS_) & 127;
    int r = (((b << 8) | ((y >> 3) << 4) | (xq >> 3)) << 6) + (y & 7)*8 + (xq & 7);
    float val = x[(size_t)t*Cdim + c] + bf2f(projout[(size_t)r*Cdim + c]);
    x2[(size_t)t*Cdim + c] = val;
    float s = val, s2 = val*val;
    #pragma unroll
    for (int off = 32; off >= 1; off >>= 1){
        s  += __shfl_xor(s,  off, 64);
        s2 += __shfl_xor(s2, off, 64);
    }
    __shared__ float red[4];
    int wv = threadIdx.x >> 6;
    if ((threadIdx.x & 63) == 0){ red[wv*2] = s; red[wv*2+1] = s2; }
    __syncthreads();
    float ts = red[0] + red[2], ts2 = red[1] + red[3];
    float mean = ts * (1.0f/128.0f);
    float var  = ts2 * (1.0f/128.0f) - mean*mean;
    float inv  = rsqrtf(var + 1e-5f);
    outp[(size_t)t*Cdim + c] = f2bf((val - mean) * inv * g[c] + bsh[c]);
}

// ---------------- Registers-only MFMA GEMM: C = A[M,K] @ Bw[N,K]^T + bias -------
// 128x128 tile, 4 waves 2x2 (each 64x64). No LDS, no barriers.
// MODE 0: qkv scatter (q scaled, k normal, v TRANSPOSED [w][h][d][n])
// MODE 1: plain bf16
template<int K, int N, int MODE>
__global__ void __launch_bounds__(256) gemm_kernel(
        const u16* __restrict__ A, const u16* __restrict__ Bw,
        const float* __restrict__ bias,
        void* __restrict__ o0, u16* __restrict__ o1, u16* __restrict__ o2,
        const float* __restrict__ resid)
{
    int t = threadIdx.x;
    int wave = t >> 6, lane = t & 63;
    int wr = wave & 1, wc = wave >> 1;
    int m = lane & 15, quad = lane >> 4;
    size_t rowbase = (size_t)blockIdx.x * 128 + wr*64;
    size_t nb      = (size_t)blockIdx.y * 128 + wc*64;

    f32x4 acc[4][4] = {};

    #pragma unroll 4
    for (int s = 0; s < K/32; s++){
        bf16x8 aq[4], bk[4];
        #pragma unroll
        for (int i = 0; i < 4; i++)
            aq[i] = *(const bf16x8*)&A[(rowbase + i*16 + m)*K + s*32 + quad*8];
        #pragma unroll
        for (int j = 0; j < 4; j++)
            bk[j] = *(const bf16x8*)&Bw[(nb + j*16 + m)*K + s*32 + quad*8];
        #pragma unroll
        for (int i = 0; i < 4; i++)
            #pragma unroll
            for (int j = 0; j < 4; j++)
                acc[i][j] = __builtin_amdgcn_mfma_f32_16x16x32_bf16(
                                aq[i], bk[j], acc[i][j], 0, 0, 0);
    }

    #pragma unroll
    for (int i = 0; i < 4; i++){
        #pragma unroll
        for (int j = 0; j < 4; j++){
            int c = (int)nb + j*16 + m;
            float bia = bias[c];
            #pragma unroll
            for (int rg = 0; rg < 4; rg++){
                int r = (int)rowbase + i*16 + quad*4 + rg;
                float v = acc[i][j][rg] + bia;
                if (MODE == 0){
                    int which = c >> 7;          // 0=q 1=k 2=v
                    int h = (c >> 5) & 3;
                    int d = c & 31;
                    int w = r >> 6, n = r & 63;
                    if (which == 0){
                        ((u16*)o0)[((size_t)(w*NH + h)*Ntok + n)*Dh + d] =
                            f2bf(v * 0.17677669529663687f);
                    } else if (which == 1){
                        o1[((size_t)(w*NH + h)*Ntok + n)*Dh + d] = f2bf(v);
                    } else {   // v transposed: [w][h][d][n]
                        o2[((size_t)(w*NH + h)*Dh + d)*Ntok + n] = f2bf(v);
                    }
                } else {
                    ((u16*)o0)[(size_t)r*N + c] = f2bf(v);
                }
            }
        }
    }
}

// ---------------- Fused MLP (round-2 structure + fast_gelu) --------------------
// 1024 blocks x 256 threads (4 waves, 2x2 over the 128x128 out tile).
// K=512 hidden dim in 4 chunks of 128; per chunk: H = GELU(A@W1c^T+b1) -> LDS
// -> O += H @ W2c^T. Weights (256 KB bf16) stay L2-resident.
__global__ void __launch_bounds__(256, 2) mlp_kernel(
        const u16* __restrict__ A,       // ln2out [Mrows][128] bf16
        const u16* __restrict__ W1,      // fc1w   [512][128]   bf16
        const float* __restrict__ b1,
        const u16* __restrict__ W2,      // fc2w   [128][512]   bf16
        const float* __restrict__ b2,
        const float* __restrict__ resid, // x2     [Mrows][128] fp32
        float* __restrict__ outp)        // out    [Mrows][128] fp32
{
    __shared__ __align__(16) u16 Asm[128*HPAD];
    __shared__ __align__(16) u16 Hsm[128*HPAD];
    int t = threadIdx.x;
    int wave = t >> 6, lane = t & 63;
    int wr = wave & 1, wc = wave >> 1;
    int m = lane & 15, quad = lane >> 4;
    size_t rowbase = (size_t)blockIdx.x * 128;

    // stage A tile (128 rows x 128 cols bf16 = 2048 x 16 B) into LDS
    #pragma unroll
    for (int it = 0; it < 8; it++){
        int idx = it*256 + t;            // 16 chunks of 16 B per row
        int r = idx >> 4, c16 = idx & 15;
        bf16x8 vv = *(const bf16x8*)&A[(rowbase + r)*Cdim + c16*8];
        *(bf16x8*)&Asm[r*HPAD + c16*8] = vv;
    }
    __syncthreads();

    f32x4 O[4][4] = {};                  // persistent 64x64 out tile per wave

    for (int kk = 0; kk < 4; kk++){
        // ---- H chunk: Hc = GELU(A @ W1[kk*128 ..][:]^T + b1) ----
        f32x4 Hacc[4][4] = {};
        #pragma unroll
        for (int s = 0; s < 4; s++){
            bf16x8 aq[4], bk[4];
            #pragma unroll
            for (int i = 0; i < 4; i++)
                aq[i] = *(const bf16x8*)&Asm[(wr*64 + i*16 + m)*HPAD + s*32 + quad*8];
            #pragma unroll
            for (int j = 0; j < 4; j++)
                bk[j] = *(const bf16x8*)&W1[(size_t)(kk*128 + wc*64 + j*16 + m)*Cdim
                                            + s*32 + quad*8];
            #pragma unroll
            for (int i = 0; i < 4; i++)
                #pragma unroll
                for (int j = 0; j < 4; j++)
                    Hacc[i][j] = __builtin_amdgcn_mfma_f32_16x16x32_bf16(
                                     aq[i], bk[j], Hacc[i][j], 0, 0, 0);
        }
        #pragma unroll
        for (int i = 0; i < 4; i++){
            #pragma unroll
            for (int j = 0; j < 4; j++){
                int hc = wc*64 + j*16 + m;          // hidden col within chunk
                float bia = b1[kk*128 + hc];
                #pragma unroll
                for (int rg = 0; rg < 4; rg++){
                    int r = wr*64 + i*16 + quad*4 + rg;
                    Hsm[r*HPAD + hc] = f2bf(fast_gelu(Hacc[i][j][rg] + bia));
                }
            }
        }
        __syncthreads();

        // ---- O += Hc @ W2[:, kk*128 ..]^T ----
        #pragma unroll
        for (int s = 0; s < 4; s++){
            bf16x8 pa[4], bk[4];
            #pragma unroll
            for (int i = 0; i < 4; i++)
                pa[i] = *(const bf16x8*)&Hsm[(wr*64 + i*16 + m)*HPAD + s*32 + quad*8];
            #pragma unroll
            for (int j = 0; j < 4; j++)
                bk[j] = *(const bf16x8*)&W2[(size_t)(wc*64 + j*16 + m)*HIDDEN
                                            + kk*128 + s*32 + quad*8];
            #pragma unroll
            for (int i = 0; i < 4; i++)
                #pragma unroll
                for (int j = 0; j < 4; j++)
                    O[i][j] = __builtin_amdgcn_mfma_f32_16x16x32_bf16(
                                  pa[i], bk[j], O[i][j], 0, 0, 0);
        }
        __syncthreads();   // Hsm reused next chunk
    }

    // ---- epilogue: + b2 + residual -> fp32 out ----
    #pragma unroll
    for (int i = 0; i < 4; i++){
        #pragma unroll
        for (int j = 0; j < 4; j++){
            int c = wc*64 + j*16 + m;
            float bia = b2[c];
            #pragma unroll
            for (int rg = 0; rg < 4; rg++){
                size_t r = rowbase + wr*64 + i*16 + quad*4 + rg;
                outp[r*Cdim + c] = resid[r*Cdim + c] + O[i][j][rg] + bia;
            }
        }
    }
}

// ------- Fused attention + proj: block = window, wave = head -------------------
// After PV, the 64x128 head-concat tile is staged in LDS (reusing the P region),
// the 64x128x128 proj GEMM runs in-block (projw L2-resident), and the result is
// stored with coalesced 16 B/lane stores. Eliminates the attno round trip.
__global__ void __launch_bounds__(256) attnproj_kernel(
        const u16* __restrict__ qb, const u16* __restrict__ kb,
        const u16* __restrict__ vt, const float* __restrict__ bmt,
        const u16* __restrict__ pw, const float* __restrict__ pb,
        u16* __restrict__ projout)
{
    __shared__ __align__(16) u16 SH[NH*64*PSTR];   // 36864 B; P + (union) Osm
    int w = blockIdx.x;
    int win = w & 255;
    int wy = win >> 4, wx = win & 15;
    int cls = ((wy == 15) ? 2 : 0) | ((wx == 15) ? 1 : 0);
    int t = threadIdx.x;
    int h = t >> 6, lane = t & 63;
    int m = lane & 15, quad = lane >> 4;
    u16* Ph  = SH + h*64*PSTR;     // per-wave private P rows
    u16* Osm = SH;                 // 64 x OSTR union view (after barrier 1)

    const u16* qg = qb + (size_t)(w*NH + h)*2048;   // [n][d]
    const u16* kg = kb + (size_t)(w*NH + h)*2048;   // [n][d]
    const u16* vg = vt + (size_t)(w*NH + h)*2048;   // [d][n] (transposed)
    const float* bm = bmt + (size_t)(cls*NH + h)*4096;

    // S = Q @ K^T  (64x64, one K=32 step)
    bf16x8 aq[4], bk[4];
    #pragma unroll
    for (int i = 0; i < 4; i++)
        aq[i] = *(const bf16x8*)&qg[(i*16 + m)*32 + quad*8];
    #pragma unroll
    for (int j = 0; j < 4; j++)
        bk[j] = *(const bf16x8*)&kg[(j*16 + m)*32 + quad*8];
    f32x4 S[4][4] = {};
    #pragma unroll
    for (int i = 0; i < 4; i++)
        #pragma unroll
        for (int j = 0; j < 4; j++)
            S[i][j] = __builtin_amdgcn_mfma_f32_16x16x32_bf16(
                          aq[i], bk[j], S[i][j], 0, 0, 0);

    // bias+mask add, row softmax -> P (bf16, per-wave private; no barrier)
    #pragma unroll
    for (int i = 0; i < 4; i++){
        #pragma unroll
        for (int rg = 0; rg < 4; rg++){
            int row = i*16 + quad*4 + rg;
            float s0 = S[i][0][rg] + bm[row*64 +  0 + m];
            float s1 = S[i][1][rg] + bm[row*64 + 16 + m];
            float s2 = S[i][2][rg] + bm[row*64 + 32 + m];
            float s3 = S[i][3][rg] + bm[row*64 + 48 + m];
            float mx = fmaxf(fmaxf(s0, s1), fmaxf(s2, s3));
            mx = fmaxf(mx, __shfl_xor(mx, 1, 64));
            mx = fmaxf(mx, __shfl_xor(mx, 2, 64));
            mx = fmaxf(mx, __shfl_xor(mx, 4, 64));
            mx = fmaxf(mx, __shfl_xor(mx, 8, 64));
            s0 = __expf(s0 - mx); s1 = __expf(s1 - mx);
            s2 = __expf(s2 - mx); s3 = __expf(s3 - mx);
            float sm = s0 + s1 + s2 + s3;
            sm += __shfl_xor(sm, 1, 64);
            sm += __shfl_xor(sm, 2, 64);
            sm += __shfl_xor(sm, 4, 64);
            sm += __shfl_xor(sm, 8, 64);
            float rinv = 1.0f / sm;
            u16* pr = &Ph[row*PSTR];
            pr[ 0 + m] = f2bf(s0 * rinv);
            pr[16 + m] = f2bf(s1 * rinv);
            pr[32 + m] = f2bf(s2 * rinv);
            pr[48 + m] = f2bf(s3 * rinv);
        }
    }

    // O = P @ V  (64x32, two K=32 steps)
    f32x4 O[4][2] = {};
    #pragma unroll
    for (int s2 = 0; s2 < 2; s2++){
        bf16x8 pa[4], bv[2];
        #pragma unroll
        for (int i = 0; i < 4; i++)
            pa[i] = *(const bf16x8*)&Ph[(i*16 + m)*PSTR + s2*32 + quad*8];
        #pragma unroll
        for (int dt = 0; dt < 2; dt++)
            bv[dt] = *(const bf16x8*)&vg[(dt*16 + m)*64 + s2*32 + quad*8];
        #pragma unroll
        for (int i = 0; i < 4; i++)
            #pragma unroll
            for (int dt = 0; dt < 2; dt++)
                O[i][dt] = __builtin_amdgcn_mfma_f32_16x16x32_bf16(
                               pa[i], bv[dt], O[i][dt], 0, 0, 0);
    }

    __syncthreads();   // all P reads done; SH is reused as Osm below

    // stage head-concat tile: Osm[row][h*32 + dt*16 + m]
    #pragma unroll
    for (int i = 0; i < 4; i++)
        #pragma unroll
        for (int dt = 0; dt < 2; dt++)
            #pragma unroll
            for (int rg = 0; rg < 4; rg++)
                Osm[(i*16 + quad*4 + rg)*OSTR + h*Dh + dt*16 + m] =
                    f2bf(O[i][dt][rg]);
    __syncthreads();

    // proj GEMM: 64x128x128; wave h covers out cols [h*32, h*32+32)
    f32x4 pacc[4][2] = {};
    #pragma unroll
    for (int s = 0; s < 4; s++){
        bf16x8 pa[4], pbk[2];
        #pragma unroll
        for (int i = 0; i < 4; i++)
            pa[i] = *(const bf16x8*)&Osm[(i*16 + m)*OSTR + s*32 + quad*8];
        #pragma unroll
        for (int j = 0; j < 2; j++)
            pbk[j] = *(const bf16x8*)&pw[(size_t)(h*Dh + j*16 + m)*Cdim
                                         + s*32 + quad*8];
        #pragma unroll
        for (int i = 0; i < 4; i++)
            #pragma unroll
            for (int j = 0; j < 2; j++)
                pacc[i][j] = __builtin_amdgcn_mfma_f32_16x16x32_bf16(
                                 pa[i], pbk[j], pacc[i][j], 0, 0, 0);
    }
    __syncthreads();   // all Osm reads done

    // stage proj result (+bias) back into Osm
    #pragma unroll
    for (int i = 0; i < 4; i++)
        #pragma unroll
        for (int j = 0; j < 2; j++){
            int c = h*Dh + j*16 + m;
            float bia = pb[c];
            #pragma unroll
            for (int rg = 0; rg < 4; rg++)
                Osm[(i*16 + quad*4 + rg)*OSTR + c] = f2bf(pacc[i][j][rg] + bia);
        }
    __syncthreads();

    // coalesced store: 64 rows x 128 u16 = 1024 chunks of 16 B
    #pragma unroll
    for (int it = 0; it < 4; it++){
        int idx = it*256 + t;
        int r = idx >> 4, c16 = idx & 15;
        *(bf16x8*)&projout[((size_t)w*64 + r)*Cdim + c16*8] =
            *(const bf16x8*)&Osm[r*OSTR + c16*8];
    }
}

extern "C" void kernel_launch(void* const* d_in, const int* in_sizes, int n_in,
                              void* d_out, int out_size, void* d_ws, size_t ws_size,
                              hipStream_t stream) {
    const float* x     = (const float*)d_in[0];
    const float* rpb   = (const float*)d_in[1];
    const float* n1g   = (const float*)d_in[2];
    const float* n1b   = (const float*)d_in[3];
    const float* qkvw  = (const float*)d_in[4];
    const float* qkvb  = (const float*)d_in[5];
    const float* projw = (const float*)d_in[6];
    const float* projb = (const float*)d_in[7];
    const float* n2g   = (const float*)d_in[8];
    const float* n2b   = (const float*)d_in[9];
    const float* fc1w  = (const float*)d_in[10];
    const float* fc1b  = (const float*)d_in[11];
    const float* fc2w  = (const float*)d_in[12];
    const float* fc2b  = (const float*)d_in[13];
    float* out = (float*)d_out;

    if (ws_size < (size_t)230u * 1024u * 1024u) return;

    // Disjoint-lifetime layout (race-free):
    //   region        offset   size   lifetime
    //   ln1out        0        32M    s1 -> s2
    //   projout       0        32M    s3 -> s4   (ln1out dead)
    //   qbuf          32M      32M    s2 -> s3
    //   kbuf          64M      32M    s2 -> s3
    //   vbuf          96M      32M    s2 -> s3
    //   x2            128M     64M    s4 -> s5
    //   ln2out        192M     32M    s4 -> s5
    //   weights/bmt   224M     ~2M    s0 -> end
    char* ws = (char*)d_ws;
    u16*  ln1out  = (u16*)(ws);
    u16*  projout = (u16*)(ws);
    u16*  qbuf    = (u16*)(ws + ((size_t)32  << 20));
    u16*  kbuf    = (u16*)(ws + ((size_t)64  << 20));
    u16*  vbuf    = (u16*)(ws + ((size_t)96  << 20));
    float* x2     = (float*)(ws + ((size_t)128 << 20));
    u16*  ln2out  = (u16*)(ws + ((size_t)192 << 20));
    u16*  wb      = (u16*)(ws + ((size_t)224 << 20));
    u16*  qkvw_b  = wb;                // 49152
    u16*  projw_b = wb + 49152;        // 16384
    u16*  fc1w_b  = wb + 65536;        // 65536
    u16*  fc2w_b  = wb + 131072;       // 65536
    float* bmt    = (float*)(ws + ((size_t)225 << 20)); // 256 KiB

    // 0. weight conversions + bias/mask table
    cvt_kernel<<<(49152+255)/256, 256, 0, stream>>>(qkvw, qkvw_b, 49152);
    cvt_kernel<<<(16384+255)/256, 256, 0, stream>>>(projw, projw_b, 16384);
    cvt_kernel<<<(65536+255)/256, 256, 0, stream>>>(fc1w, fc1w_b, 65536);
    cvt_kernel<<<(65536+255)/256, 256, 0, stream>>>(fc2w, fc2w_b, 65536);
    bm_kernel<<<256, 256, 0, stream>>>(rpb, bmt);

    // 1. LN1 + shift + window partition
    ln1_kernel<<<Mrows, 128, 0, stream>>>(x, n1g, n1b, ln1out);
    // 2. QKV GEMM (q/k per-head, v transposed)
    gemm_kernel<128, 384, 0><<<dim3(Mrows/128, 3), 256, 0, stream>>>(
        ln1out, qkvw_b, qkvb, qbuf, kbuf, vbuf, nullptr);
    // 3. fused MFMA windowed attention + proj (block = window)
    attnproj_kernel<<<WTOT, 256, 0, stream>>>(qbuf, kbuf, vbuf, bmt,
                                              projw_b, projb, projout);
    // 4. fused window-reverse + unshift + residual + LN2 (disjoint in/out)
    resln_kernel<<<Mrows, 128, 0, stream>>>(x, projout, n2g, n2b, x2, ln2out);
    // 5. fused MLP: out = x2 + GELU(ln2out @ fc1^T + b1) @ fc2^T + b2
    mlp_kernel<<<Mrows/128, 256, 0, stream>>>(
        ln2out, fc1w_b, fc1b, fc2w_b, fc2b, x2, out);
}

// Round 5
// 433.306 us; speedup vs baseline: 1.2629x; 1.1269x over previous
//
#include <hip/hip_runtime.h>
#include <math.h>

typedef unsigned short u16;
typedef unsigned int   u32;

#define SS_    4
#define NH     4
#define Dh     32
#define Cdim   128
#define Ntok   64
#define WTOT   2048
#define Mrows  131072   // WTOT * Ntok
#define HIDDEN 512
#define PSTR   72       // attn P LDS row stride (u16)
#define OSTR   136      // attn Osm row stride (u16): 272 B, 16-B aligned
#define HPAD   136      // MLP LDS row stride (u16): 272 B, 16-B aligned

typedef __bf16 bf16x8 __attribute__((ext_vector_type(8)));
typedef u16    u16x8  __attribute__((ext_vector_type(8)));
typedef float  f32x4  __attribute__((ext_vector_type(4)));

__device__ __forceinline__ float bf2f(u16 u){
    union {u32 i; float f;} v; v.i = ((u32)u) << 16; return v.f;
}
__device__ __forceinline__ u16 f2bf(float f){
    union {float f; u32 i;} v; v.f = f;
    u32 x = v.i;
    return (u16)((x + 0x7fffu + ((x >> 16) & 1u)) >> 16);
}

// GELU with A&S 7.1.26 erf approx (max err 1.5e-7)
__device__ __forceinline__ float fast_gelu(float v){
    float a = v * 0.70710678118654752f;
    float x = fabsf(a);
    float t = 1.0f / (1.0f + 0.3275911f * x);
    float p = ((((1.061405429f*t - 1.453152027f)*t + 1.421413741f)*t
                - 0.284496736f)*t + 0.254829592f)*t;
    float e = __expf(-x*x);
    float er = copysignf(1.0f - p*e, a);
    return 0.5f * v * (1.0f + er);
}

// token (windowed row) -> original token index (bijection, shift +4 both dims)
__device__ __forceinline__ int map_row_to_token(int r){
    int w = r >> 6, n = r & 63;
    int b = w >> 8, win = w & 255;
    int wy = win >> 4, wx = win & 15;
    int iy = n >> 3, ix = n & 7;
    int ro = (wy*8 + iy + SS_) & 127;
    int co = (wx*8 + ix + SS_) & 127;
    return (b << 14) + (ro << 7) + co;
}

// token index -> windowed row (inverse map, used by fused res+LN2+MLP)
__device__ __forceinline__ int map_token_to_row(int t){
    int b = t >> 14, ro = (t >> 7) & 127, co = t & 127;
    int y  = (ro + 128 - SS_) & 127;
    int xq = (co + 128 - SS_) & 127;
    return (((b << 8) | ((y >> 3) << 4) | (xq >> 3)) << 6) + (y & 7)*8 + (xq & 7);
}

// ---------------- fp32 -> bf16 weight conversion ----------------
__global__ void __launch_bounds__(256) cvt_kernel(const float* __restrict__ src,
        u16* __restrict__ dst, int n)
{
    int i = blockIdx.x * 256 + threadIdx.x;
    if (i < n) dst[i] = f2bf(src[i]);
}

// ---------------- bias+mask table: bm[cls][h][row][col], 4*4*64*64 fp32 ----------
__global__ void __launch_bounds__(256) bm_kernel(const float* __restrict__ rpb,
        float* __restrict__ bmt)
{
    int e = blockIdx.x * 256 + threadIdx.x;     // 65536 total
    int cls = e >> 14, h = (e >> 12) & 3, row = (e >> 6) & 63, col = e & 63;
    int iy = row >> 3, ix = row & 7, jy = col >> 3, jx = col & 7;
    int bidx = (iy - jy + 7)*15 + (ix - jx + 7);
    float bias = rpb[bidx*NH + h];
    int ybit = cls >> 1, xbit = cls & 1;
    int ri = (ybit ? (iy < 4 ? 1 : 2) : 0)*3 + (xbit ? (ix < 4 ? 1 : 2) : 0);
    int rj = (ybit ? (jy < 4 ? 1 : 2) : 0)*3 + (xbit ? (jx < 4 ? 1 : 2) : 0);
    bmt[e] = bias + ((ri != rj) ? -100.0f : 0.0f);
}

// ---------------- LayerNorm 1 (fp32 in, bf16 windowed out) ----------------
__global__ void __launch_bounds__(128) ln1_kernel(const float* __restrict__ xin,
        const float* __restrict__ g, const float* __restrict__ bsh,
        u16* __restrict__ outp)
{
    int t = blockIdx.x;
    int c = threadIdx.x;
    int src = map_row_to_token(t);
    float val = xin[(size_t)src*Cdim + c];
    float s = val, s2 = val*val;
    #pragma unroll
    for (int off = 32; off >= 1; off >>= 1){
        s  += __shfl_xor(s,  off, 64);
        s2 += __shfl_xor(s2, off, 64);
    }
    __shared__ float red[4];
    int wv = threadIdx.x >> 6;
    if ((threadIdx.x & 63) == 0){ red[wv*2] = s; red[wv*2+1] = s2; }
    __syncthreads();
    float ts = red[0] + red[2], ts2 = red[1] + red[3];
    float mean = ts * (1.0f/128.0f);
    float var  = ts2 * (1.0f/128.0f) - mean*mean;
    float inv  = rsqrtf(var + 1e-5f);
    outp[(size_t)t*Cdim + c] = f2bf((val - mean) * inv * g[c] + bsh[c]);
}

// ---------------- Registers-only MFMA GEMM: C = A[M,K] @ Bw[N,K]^T + bias -------
// 128x128 tile, 4 waves 2x2 (each 64x64). No LDS, no barriers.
// MODE 0: qkv scatter (q scaled, k normal, v TRANSPOSED [w][h][d][n])
// MODE 1: plain bf16
template<int K, int N, int MODE>
__global__ void __launch_bounds__(256) gemm_kernel(
        const u16* __restrict__ A, const u16* __restrict__ Bw,
        const float* __restrict__ bias,
        void* __restrict__ o0, u16* __restrict__ o1, u16* __restrict__ o2,
        const float* __restrict__ resid)
{
    int t = threadIdx.x;
    int wave = t >> 6, lane = t & 63;
    int wr = wave & 1, wc = wave >> 1;
    int m = lane & 15, quad = lane >> 4;
    size_t rowbase = (size_t)blockIdx.x * 128 + wr*64;
    size_t nb      = (size_t)blockIdx.y * 128 + wc*64;

    f32x4 acc[4][4] = {};

    #pragma unroll 4
    for (int s = 0; s < K/32; s++){
        bf16x8 aq[4], bk[4];
        #pragma unroll
        for (int i = 0; i < 4; i++)
            aq[i] = *(const bf16x8*)&A[(rowbase + i*16 + m)*K + s*32 + quad*8];
        #pragma unroll
        for (int j = 0; j < 4; j++)
            bk[j] = *(const bf16x8*)&Bw[(nb + j*16 + m)*K + s*32 + quad*8];
        #pragma unroll
        for (int i = 0; i < 4; i++)
            #pragma unroll
            for (int j = 0; j < 4; j++)
                acc[i][j] = __builtin_amdgcn_mfma_f32_16x16x32_bf16(
                                aq[i], bk[j], acc[i][j], 0, 0, 0);
    }

    #pragma unroll
    for (int i = 0; i < 4; i++){
        #pragma unroll
        for (int j = 0; j < 4; j++){
            int c = (int)nb + j*16 + m;
            float bia = bias[c];
            #pragma unroll
            for (int rg = 0; rg < 4; rg++){
                int r = (int)rowbase + i*16 + quad*4 + rg;
                float v = acc[i][j][rg] + bia;
                if (MODE == 0){
                    int which = c >> 7;          // 0=q 1=k 2=v
                    int h = (c >> 5) & 3;
                    int d = c & 31;
                    int w = r >> 6, n = r & 63;
                    if (which == 0){
                        ((u16*)o0)[((size_t)(w*NH + h)*Ntok + n)*Dh + d] =
                            f2bf(v * 0.17677669529663687f);
                    } else if (which == 1){
                        o1[((size_t)(w*NH + h)*Ntok + n)*Dh + d] = f2bf(v);
                    } else {   // v transposed: [w][h][d][n]
                        o2[((size_t)(w*NH + h)*Dh + d)*Ntok + n] = f2bf(v);
                    }
                } else {
                    ((u16*)o0)[(size_t)r*N + c] = f2bf(v);
                }
            }
        }
    }
}

// --- Fused residual + LN2 + MLP:
//   out = (x + proj~) + GELU(LN2(x + proj~) @ W1^T + b1) @ W2^T + b2
// where proj~ = window-reverse+unshift of projout. Replaces resln_kernel +
// mlp_kernel: x2/ln2out intermediates never touch HBM.
// 1024 blocks x 256 threads (4 waves, 2x2 over the 128x128 out tile).
// Stage: each 16-lane group owns one row -> row LN via shfl_xor(1..8).
__global__ void __launch_bounds__(256, 2) mlp_kernel(
        const float* __restrict__ x,     // [Mrows][128] fp32, token order
        const u16* __restrict__ projout, // [Mrows][128] bf16, windowed order
        const float* __restrict__ g, const float* __restrict__ bsh,
        const u16* __restrict__ W1,      // fc1w [512][128] bf16
        const float* __restrict__ b1,
        const u16* __restrict__ W2,      // fc2w [128][512] bf16
        const float* __restrict__ b2,
        float* __restrict__ outp)        // out  [Mrows][128] fp32
{
    __shared__ __align__(16) u16 Asm[128*HPAD];
    __shared__ __align__(16) u16 Hsm[128*HPAD];
    int t = threadIdx.x;
    int wave = t >> 6, lane = t & 63;
    int wr = wave & 1, wc = wave >> 1;
    int m = lane & 15, quad = lane >> 4;
    size_t rowbase = (size_t)blockIdx.x * 128;

    // ---- fused stage: val = x + proj~, LN2 -> bf16 Asm tile ----
    #pragma unroll
    for (int it = 0; it < 8; it++){
        int idx  = it*256 + t;
        int r    = idx >> 4;            // tile row (token order); const per 16-lane grp
        int c8   = idx & 15;            // 8-col chunk = lane&15
        int trow = (int)rowbase + r;
        int rr   = map_token_to_row(trow);
        f32x4 xa = *(const f32x4*)&x[(size_t)trow*Cdim + c8*8];
        f32x4 xb = *(const f32x4*)&x[(size_t)trow*Cdim + c8*8 + 4];
        u16x8 pv = *(const u16x8*)&projout[(size_t)rr*Cdim + c8*8];
        float val[8];
        float s = 0.0f, s2 = 0.0f;
        #pragma unroll
        for (int k = 0; k < 8; k++){
            float xv = (k < 4) ? xa[k] : xb[k-4];
            val[k] = xv + bf2f(pv[k]);
            s += val[k]; s2 += val[k]*val[k];
        }
        #pragma unroll
        for (int off = 1; off <= 8; off <<= 1){
            s  += __shfl_xor(s,  off, 64);
            s2 += __shfl_xor(s2, off, 64);
        }
        float mean = s * (1.0f/128.0f);
        float var  = s2 * (1.0f/128.0f) - mean*mean;
        float inv  = rsqrtf(var + 1e-5f);
        f32x4 ga = *(const f32x4*)&g[c8*8],  gb = *(const f32x4*)&g[c8*8 + 4];
        f32x4 ba = *(const f32x4*)&bsh[c8*8], bb = *(const f32x4*)&bsh[c8*8 + 4];
        u16x8 ov;
        #pragma unroll
        for (int k = 0; k < 8; k++){
            float gv = (k < 4) ? ga[k] : gb[k-4];
            float bv = (k < 4) ? ba[k] : bb[k-4];
            ov[k] = f2bf((val[k] - mean) * inv * gv + bv);
        }
        *(u16x8*)&Asm[r*HPAD + c8*8] = ov;
    }
    __syncthreads();

    f32x4 O[4][4] = {};                  // persistent 64x64 out tile per wave

    for (int kk = 0; kk < 4; kk++){
        // ---- H chunk: Hc = GELU(A @ W1[kk*128 ..][:]^T + b1) ----
        f32x4 Hacc[4][4] = {};
        #pragma unroll
        for (int s = 0; s < 4; s++){
            bf16x8 aq[4], bk[4];
            #pragma unroll
            for (int i = 0; i < 4; i++)
                aq[i] = *(const bf16x8*)&Asm[(wr*64 + i*16 + m)*HPAD + s*32 + quad*8];
            #pragma unroll
            for (int j = 0; j < 4; j++)
                bk[j] = *(const bf16x8*)&W1[(size_t)(kk*128 + wc*64 + j*16 + m)*Cdim
                                            + s*32 + quad*8];
            #pragma unroll
            for (int i = 0; i < 4; i++)
                #pragma unroll
                for (int j = 0; j < 4; j++)
                    Hacc[i][j] = __builtin_amdgcn_mfma_f32_16x16x32_bf16(
                                     aq[i], bk[j], Hacc[i][j], 0, 0, 0);
        }
        #pragma unroll
        for (int i = 0; i < 4; i++){
            #pragma unroll
            for (int j = 0; j < 4; j++){
                int hc = wc*64 + j*16 + m;          // hidden col within chunk
                float bia = b1[kk*128 + hc];
                #pragma unroll
                for (int rg = 0; rg < 4; rg++){
                    int r = wr*64 + i*16 + quad*4 + rg;
                    Hsm[r*HPAD + hc] = f2bf(fast_gelu(Hacc[i][j][rg] + bia));
                }
            }
        }
        __syncthreads();

        // ---- O += Hc @ W2[:, kk*128 ..]^T ----
        #pragma unroll
        for (int s = 0; s < 4; s++){
            bf16x8 pa[4], bk[4];
            #pragma unroll
            for (int i = 0; i < 4; i++)
                pa[i] = *(const bf16x8*)&Hsm[(wr*64 + i*16 + m)*HPAD + s*32 + quad*8];
            #pragma unroll
            for (int j = 0; j < 4; j++)
                bk[j] = *(const bf16x8*)&W2[(size_t)(wc*64 + j*16 + m)*HIDDEN
                                            + kk*128 + s*32 + quad*8];
            #pragma unroll
            for (int i = 0; i < 4; i++)
                #pragma unroll
                for (int j = 0; j < 4; j++)
                    O[i][j] = __builtin_amdgcn_mfma_f32_16x16x32_bf16(
                                  pa[i], bk[j], O[i][j], 0, 0, 0);
        }
        __syncthreads();   // Hsm reused next chunk
    }

    // ---- epilogue: out = (x + proj~) + O + b2 (x/proj re-read; L2-hot) ----
    #pragma unroll
    for (int i = 0; i < 4; i++){
        #pragma unroll
        for (int rg = 0; rg < 4; rg++){
            int r  = (int)rowbase + wr*64 + i*16 + quad*4 + rg;   // token row
            int rr = map_token_to_row(r);
            #pragma unroll
            for (int j = 0; j < 4; j++){
                int c = wc*64 + j*16 + m;
                float v = x[(size_t)r*Cdim + c] + bf2f(projout[(size_t)rr*Cdim + c])
                          + O[i][j][rg] + b2[c];
                outp[(size_t)r*Cdim + c] = v;
            }
        }
    }
}

// ------- Fused attention + proj: block = window, wave = head -------------------
__global__ void __launch_bounds__(256) attnproj_kernel(
        const u16* __restrict__ qb, const u16* __restrict__ kb,
        const u16* __restrict__ vt, const float* __restrict__ bmt,
        const u16* __restrict__ pw, const float* __restrict__ pb,
        u16* __restrict__ projout)
{
    __shared__ __align__(16) u16 SH[NH*64*PSTR];   // 36864 B; P + (union) Osm
    int w = blockIdx.x;
    int win = w & 255;
    int wy = win >> 4, wx = win & 15;
    int cls = ((wy == 15) ? 2 : 0) | ((wx == 15) ? 1 : 0);
    int t = threadIdx.x;
    int h = t >> 6, lane = t & 63;
    int m = lane & 15, quad = lane >> 4;
    u16* Ph  = SH + h*64*PSTR;     // per-wave private P rows
    u16* Osm = SH;                 // 64 x OSTR union view (after barrier 1)

    const u16* qg = qb + (size_t)(w*NH + h)*2048;   // [n][d]
    const u16* kg = kb + (size_t)(w*NH + h)*2048;   // [n][d]
    const u16* vg = vt + (size_t)(w*NH + h)*2048;   // [d][n] (transposed)
    const float* bm = bmt + (size_t)(cls*NH + h)*4096;

    // S = Q @ K^T  (64x64, one K=32 step)
    bf16x8 aq[4], bk[4];
    #pragma unroll
    for (int i = 0; i < 4; i++)
        aq[i] = *(const bf16x8*)&qg[(i*16 + m)*32 + quad*8];
    #pragma unroll
    for (int j = 0; j < 4; j++)
        bk[j] = *(const bf16x8*)&kg[(j*16 + m)*32 + quad*8];
    f32x4 S[4][4] = {};
    #pragma unroll
    for (int i = 0; i < 4; i++)
        #pragma unroll
        for (int j = 0; j < 4; j++)
            S[i][j] = __builtin_amdgcn_mfma_f32_16x16x32_bf16(
                          aq[i], bk[j], S[i][j], 0, 0, 0);

    // bias+mask add, row softmax -> P (bf16, per-wave private; no barrier)
    #pragma unroll
    for (int i = 0; i < 4; i++){
        #pragma unroll
        for (int rg = 0; rg < 4; rg++){
            int row = i*16 + quad*4 + rg;
            float s0 = S[i][0][rg] + bm[row*64 +  0 + m];
            float s1 = S[i][1][rg] + bm[row*64 + 16 + m];
            float s2 = S[i][2][rg] + bm[row*64 + 32 + m];
            float s3 = S[i][3][rg] + bm[row*64 + 48 + m];
            float mx = fmaxf(fmaxf(s0, s1), fmaxf(s2, s3));
            mx = fmaxf(mx, __shfl_xor(mx, 1, 64));
            mx = fmaxf(mx, __shfl_xor(mx, 2, 64));
            mx = fmaxf(mx, __shfl_xor(mx, 4, 64));
            mx = fmaxf(mx, __shfl_xor(mx, 8, 64));
            s0 = __expf(s0 - mx); s1 = __expf(s1 - mx);
            s2 = __expf(s2 - mx); s3 = __expf(s3 - mx);
            float sm = s0 + s1 + s2 + s3;
            sm += __shfl_xor(sm, 1, 64);
            sm += __shfl_xor(sm, 2, 64);
            sm += __shfl_xor(sm, 4, 64);
            sm += __shfl_xor(sm, 8, 64);
            float rinv = 1.0f / sm;
            u16* pr = &Ph[row*PSTR];
            pr[ 0 + m] = f2bf(s0 * rinv);
            pr[16 + m] = f2bf(s1 * rinv);
            pr[32 + m] = f2bf(s2 * rinv);
            pr[48 + m] = f2bf(s3 * rinv);
        }
    }

    // O = P @ V  (64x32, two K=32 steps)
    f32x4 O[4][2] = {};
    #pragma unroll
    for (int s2 = 0; s2 < 2; s2++){
        bf16x8 pa[4], bv[2];
        #pragma unroll
        for (int i = 0; i < 4; i++)
            pa[i] = *(const bf16x8*)&Ph[(i*16 + m)*PSTR + s2*32 + quad*8];
        #pragma unroll
        for (int dt = 0; dt < 2; dt++)
            bv[dt] = *(const bf16x8*)&vg[(dt*16 + m)*64 + s2*32 + quad*8];
        #pragma unroll
        for (int i = 0; i < 4; i++)
            #pragma unroll
            for (int dt = 0; dt < 2; dt++)
                O[i][dt] = __builtin_amdgcn_mfma_f32_16x16x32_bf16(
                               pa[i], bv[dt], O[i][dt], 0, 0, 0);
    }

    __syncthreads();   // all P reads done; SH is reused as Osm below

    // stage head-concat tile: Osm[row][h*32 + dt*16 + m]
    #pragma unroll
    for (int i = 0; i < 4; i++)
        #pragma unroll
        for (int dt = 0; dt < 2; dt++)
            #pragma unroll
            for (int rg = 0; rg < 4; rg++)
                Osm[(i*16 + quad*4 + rg)*OSTR + h*Dh + dt*16 + m] =
                    f2bf(O[i][dt][rg]);
    __syncthreads();

    // proj GEMM: 64x128x128; wave h covers out cols [h*32, h*32+32)
    f32x4 pacc[4][2] = {};
    #pragma unroll
    for (int s = 0; s < 4; s++){
        bf16x8 pa[4], pbk[2];
        #pragma unroll
        for (int i = 0; i < 4; i++)
            pa[i] = *(const bf16x8*)&Osm[(i*16 + m)*OSTR + s*32 + quad*8];
        #pragma unroll
        for (int j = 0; j < 2; j++)
            pbk[j] = *(const bf16x8*)&pw[(size_t)(h*Dh + j*16 + m)*Cdim
                                         + s*32 + quad*8];
        #pragma unroll
        for (int i = 0; i < 4; i++)
            #pragma unroll
            for (int j = 0; j < 2; j++)
                pacc[i][j] = __builtin_amdgcn_mfma_f32_16x16x32_bf16(
                                 pa[i], pbk[j], pacc[i][j], 0, 0, 0);
    }
    __syncthreads();   // all Osm reads done

    // stage proj result (+bias) back into Osm
    #pragma unroll
    for (int i = 0; i < 4; i++)
        #pragma unroll
        for (int j = 0; j < 2; j++){
            int c = h*Dh + j*16 + m;
            float bia = pb[c];
            #pragma unroll
            for (int rg = 0; rg < 4; rg++)
                Osm[(i*16 + quad*4 + rg)*OSTR + c] = f2bf(pacc[i][j][rg] + bia);
        }
    __syncthreads();

    // coalesced store: 64 rows x 128 u16 = 1024 chunks of 16 B
    #pragma unroll
    for (int it = 0; it < 4; it++){
        int idx = it*256 + t;
        int r = idx >> 4, c16 = idx & 15;
        *(bf16x8*)&projout[((size_t)w*64 + r)*Cdim + c16*8] =
            *(const bf16x8*)&Osm[r*OSTR + c16*8];
    }
}

extern "C" void kernel_launch(void* const* d_in, const int* in_sizes, int n_in,
                              void* d_out, int out_size, void* d_ws, size_t ws_size,
                              hipStream_t stream) {
    const float* x     = (const float*)d_in[0];
    const float* rpb   = (const float*)d_in[1];
    const float* n1g   = (const float*)d_in[2];
    const float* n1b   = (const float*)d_in[3];
    const float* qkvw  = (const float*)d_in[4];
    const float* qkvb  = (const float*)d_in[5];
    const float* projw = (const float*)d_in[6];
    const float* projb = (const float*)d_in[7];
    const float* n2g   = (const float*)d_in[8];
    const float* n2b   = (const float*)d_in[9];
    const float* fc1w  = (const float*)d_in[10];
    const float* fc1b  = (const float*)d_in[11];
    const float* fc2w  = (const float*)d_in[12];
    const float* fc2b  = (const float*)d_in[13];
    float* out = (float*)d_out;

    if (ws_size < (size_t)230u * 1024u * 1024u) return;

    // Disjoint-lifetime layout (race-free):
    //   region        offset   size   lifetime
    //   ln1out        0        32M    s1 -> s2
    //   projout       0        32M    s3 -> s5   (ln1out dead after s2)
    //   qbuf          32M      32M    s2 -> s3
    //   kbuf          64M      32M    s2 -> s3
    //   vbuf          96M      32M    s2 -> s3
    //   weights/bmt   224M     ~2M    s0 -> end
    char* ws = (char*)d_ws;
    u16*  ln1out  = (u16*)(ws);
    u16*  projout = (u16*)(ws);
    u16*  qbuf    = (u16*)(ws + ((size_t)32  << 20));
    u16*  kbuf    = (u16*)(ws + ((size_t)64  << 20));
    u16*  vbuf    = (u16*)(ws + ((size_t)96  << 20));
    u16*  wb      = (u16*)(ws + ((size_t)224 << 20));
    u16*  qkvw_b  = wb;                // 49152
    u16*  projw_b = wb + 49152;        // 16384
    u16*  fc1w_b  = wb + 65536;        // 65536
    u16*  fc2w_b  = wb + 131072;       // 65536
    float* bmt    = (float*)(ws + ((size_t)225 << 20)); // 256 KiB

    // 0. weight conversions + bias/mask table
    cvt_kernel<<<(49152+255)/256, 256, 0, stream>>>(qkvw, qkvw_b, 49152);
    cvt_kernel<<<(16384+255)/256, 256, 0, stream>>>(projw, projw_b, 16384);
    cvt_kernel<<<(65536+255)/256, 256, 0, stream>>>(fc1w, fc1w_b, 65536);
    cvt_kernel<<<(65536+255)/256, 256, 0, stream>>>(fc2w, fc2w_b, 65536);
    bm_kernel<<<256, 256, 0, stream>>>(rpb, bmt);

    // 1. LN1 + shift + window partition
    ln1_kernel<<<Mrows, 128, 0, stream>>>(x, n1g, n1b, ln1out);
    // 2. QKV GEMM (q/k per-head, v transposed)
    gemm_kernel<128, 384, 0><<<dim3(Mrows/128, 3), 256, 0, stream>>>(
        ln1out, qkvw_b, qkvb, qbuf, kbuf, vbuf, nullptr);
    // 3. fused MFMA windowed attention + proj (block = window)
    attnproj_kernel<<<WTOT, 256, 0, stream>>>(qbuf, kbuf, vbuf, bmt,
                                              projw_b, projb, projout);
    // 4. fused residual + LN2 + MLP -> out (x2/ln2out never hit HBM)
    mlp_kernel<<<Mrows/128, 256, 0, stream>>>(
        x, projout, n2g, n2b, fc1w_b, fc1b, fc2w_b, fc2b, out);
}